// Round 1
// baseline (666.403 us; speedup 1.0000x reference)
//
#include <hip/hip_runtime.h>
#include <hip/hip_bf16.h>

#define WAVE 64

// ---------------------------------------------------------------------------
// Kernel 1: we[k] = sum_c We[k][c] * att_edge[c]  (per layer, 32 values each)
// ---------------------------------------------------------------------------
__global__ void we_kernel(const float* __restrict__ We1, const float* __restrict__ ae1v,
                          const float* __restrict__ We2, const float* __restrict__ ae2v,
                          float* __restrict__ we1, float* __restrict__ we2) {
    int t = threadIdx.x;            // 64 threads
    const float* W = (t < 32) ? We1 : We2;
    const float* a = (t < 32) ? ae1v : ae2v;
    float* o       = (t < 32) ? we1 : we2;
    int k = t & 31;
    float s = 0.f;
    for (int c = 0; c < 64; ++c) s += W[k * 64 + c] * a[c];
    o[k] = s;
}

// ---------------------------------------------------------------------------
// Kernel 2: per-edge a_edge for both layers + in-degree count
// ---------------------------------------------------------------------------
__global__ __launch_bounds__(256)
void edge_kernel(const float4* __restrict__ ea, const int* __restrict__ eidx,
                 const float* __restrict__ we1g, const float* __restrict__ we2g,
                 float* __restrict__ ae1, float* __restrict__ ae2,
                 int* __restrict__ cnt, int E) {
    __shared__ float w1s[32], w2s[32];
    if (threadIdx.x < 32) w1s[threadIdx.x] = we1g[threadIdx.x];
    else if (threadIdx.x < 64) w2s[threadIdx.x - 32] = we2g[threadIdx.x - 32];
    __syncthreads();
    int e = blockIdx.x * 256 + threadIdx.x;
    if (e >= E) return;
    float acc1 = 0.f, acc2 = 0.f;
#pragma unroll
    for (int q = 0; q < 8; ++q) {
        float4 v = ea[(size_t)e * 8 + q];
        acc1 += v.x * w1s[q * 4 + 0] + v.y * w1s[q * 4 + 1] +
                v.z * w1s[q * 4 + 2] + v.w * w1s[q * 4 + 3];
        acc2 += v.x * w2s[q * 4 + 0] + v.y * w2s[q * 4 + 1] +
                v.z * w2s[q * 4 + 2] + v.w * w2s[q * 4 + 3];
    }
    ae1[e] = acc1;
    ae2[e] = acc2;
    atomicAdd(&cnt[eidx[E + e]], 1);   // dst row of edge_index
}

// ---------------------------------------------------------------------------
// Kernel 3: single-block exclusive scan of cnt -> row_ptr, cursor
// ---------------------------------------------------------------------------
__global__ __launch_bounds__(1024)
void scan_kernel(const int* __restrict__ cnt, int* __restrict__ row_ptr,
                 int* __restrict__ cursor, int n) {
    __shared__ int wsum[16];
    __shared__ int wtot;
    int tid = threadIdx.x;
    int lane = tid & 63, wid = tid >> 6;
    int carry = 0;
    for (int base = 0; base < n; base += 1024) {
        int idx = base + tid;
        int v = (idx < n) ? cnt[idx] : 0;
        int s = v;
#pragma unroll
        for (int off = 1; off < 64; off <<= 1) {
            int t = __shfl_up(s, off, 64);
            if (lane >= off) s += t;
        }
        if (lane == 63) wsum[wid] = s;
        __syncthreads();
        if (tid == 0) {
            int run = 0;
            for (int w = 0; w < 16; ++w) { int t = wsum[w]; wsum[w] = run; run += t; }
            wtot = run;
        }
        __syncthreads();
        int incl = s + wsum[wid];
        if (idx < n) {
            int ex = carry + incl - v;
            row_ptr[idx] = ex;
            cursor[idx] = ex;
        }
        carry += wtot;
        __syncthreads();
    }
    if (tid == 0) row_ptr[n] = carry;
}

// ---------------------------------------------------------------------------
// Kernel 4: scatter edges into dst-sorted CSR
// ---------------------------------------------------------------------------
__global__ __launch_bounds__(256)
void scatter_kernel(const int* __restrict__ eidx, const float* __restrict__ ae1,
                    const float* __restrict__ ae2, int* __restrict__ cursor,
                    int* __restrict__ s_src, float* __restrict__ s_ae1,
                    float* __restrict__ s_ae2, int E) {
    int e = blockIdx.x * 256 + threadIdx.x;
    if (e >= E) return;
    int dst = eidx[E + e];
    int src = eidx[e];
    int pos = atomicAdd(&cursor[dst], 1);
    s_src[pos] = src;
    s_ae1[pos] = ae1[e];
    s_ae2[pos] = ae2[e];
}

// ---------------------------------------------------------------------------
// Kernel 5: H = X @ W (one wave per node, lane = out channel) + attn logits
// ---------------------------------------------------------------------------
template <int INC>
__global__ __launch_bounds__(256)
void gemm_kernel(const float* __restrict__ X, const float* __restrict__ W,
                 const float* __restrict__ asv, const float* __restrict__ adv,
                 float* __restrict__ H, float* __restrict__ a_src,
                 float* __restrict__ a_dst, int n) {
    __shared__ float Wl[INC * 64];
    for (int t = threadIdx.x; t < INC * 64; t += 256) Wl[t] = W[t];
    __syncthreads();
    int wid = threadIdx.x >> 6, lane = threadIdx.x & 63;
    int i = blockIdx.x * 4 + wid;
    if (i >= n) return;
    const float4* xr = (const float4*)(X + (size_t)i * INC);
    float acc = 0.f;
#pragma unroll
    for (int k4 = 0; k4 < INC / 4; ++k4) {
        float4 xv = xr[k4];
        acc += xv.x * Wl[(k4 * 4 + 0) * 64 + lane];
        acc += xv.y * Wl[(k4 * 4 + 1) * 64 + lane];
        acc += xv.z * Wl[(k4 * 4 + 2) * 64 + lane];
        acc += xv.w * Wl[(k4 * 4 + 3) * 64 + lane];
    }
    H[(size_t)i * 64 + lane] = acc;
    float s = acc * asv[lane];
    float d = acc * adv[lane];
#pragma unroll
    for (int off = 32; off >= 1; off >>= 1) {
        s += __shfl_xor(s, off, 64);
        d += __shfl_xor(d, off, 64);
    }
    if (lane == 0) { a_src[i] = s; a_dst[i] = d; }
}

// ---------------------------------------------------------------------------
// Kernel 6: per-node online-softmax aggregation (one wave per node)
// ---------------------------------------------------------------------------
template <bool RELU>
__global__ __launch_bounds__(256)
void agg_kernel(const int* __restrict__ row_ptr, const int* __restrict__ s_src,
                const float* __restrict__ s_ae, const float* __restrict__ a_srcv,
                const float* __restrict__ a_dstv, const float* __restrict__ H,
                const float* __restrict__ bias, float* __restrict__ out, int n) {
    int wid = threadIdx.x >> 6, lane = threadIdx.x & 63;
    int i = blockIdx.x * 4 + wid;
    if (i >= n) return;
    int start = row_ptr[i], end = row_ptr[i + 1];
    float adst = a_dstv[i];
    float m = -INFINITY, den = 0.f, acc = 0.f, aesum = 0.f;
    for (int j = start; j < end; ++j) {
        int s = s_src[j];
        float ae = s_ae[j];
        float hv = H[(size_t)s * 64 + lane];
        float al = a_srcv[s] + adst + ae;
        al = al > 0.f ? al : 0.2f * al;
        aesum += ae;
        float mn = fmaxf(m, al);
        float r = __expf(m - mn);
        float p = __expf(al - mn);
        den = den * r + p;
        acc = acc * r + p * hv;
        m = mn;
    }
    int deg = end - start;
    float ael = aesum / (float)(deg > 0 ? deg : 1);
    float al = a_srcv[i] + adst + ael;
    al = al > 0.f ? al : 0.2f * al;
    float mn = fmaxf(m, al);
    float r = __expf(m - mn);
    float p = __expf(al - mn);
    float hv = H[(size_t)i * 64 + lane];
    den = den * r + p;
    acc = acc * r + p * hv;
    float o = acc / (den + 1e-16f) + bias[lane];
    if (RELU) o = fmaxf(o, 0.f);
    out[(size_t)i * 64 + lane] = o;
}

// ---------------------------------------------------------------------------
extern "C" void kernel_launch(void* const* d_in, const int* in_sizes, int n_in,
                              void* d_out, int out_size, void* d_ws, size_t ws_size,
                              hipStream_t stream) {
    const float* x        = (const float*)d_in[0];
    const int*   eidx     = (const int*)d_in[1];
    const float* eattr    = (const float*)d_in[2];
    const float* W1       = (const float*)d_in[3];
    const float* We1      = (const float*)d_in[4];
    const float* att_src1 = (const float*)d_in[5];
    const float* att_dst1 = (const float*)d_in[6];
    const float* att_edge1= (const float*)d_in[7];
    const float* b1       = (const float*)d_in[8];
    const float* W2       = (const float*)d_in[9];
    const float* We2      = (const float*)d_in[10];
    const float* att_src2 = (const float*)d_in[11];
    const float* att_dst2 = (const float*)d_in[12];
    const float* att_edge2= (const float*)d_in[13];
    const float* b2       = (const float*)d_in[14];
    float* out = (float*)d_out;

    const int n = in_sizes[0] / 128;    // 50000
    const int E = in_sizes[1] / 2;      // 1600000

    // workspace carve-up
    char* ws = (char*)d_ws;
    size_t off = 0;
    auto carve = [&](size_t bytes) {
        char* p = ws + off;
        off = (off + bytes + 255) & ~(size_t)255;
        return p;
    };
    float* we1    = (float*)carve(32 * 4);
    float* we2    = (float*)carve(32 * 4);
    float* ae1    = (float*)carve((size_t)E * 4);
    float* ae2    = (float*)carve((size_t)E * 4);
    int*   cnt    = (int*)carve((size_t)n * 4);
    int*   row_ptr= (int*)carve((size_t)(n + 1) * 4);
    int*   cursor = (int*)carve((size_t)n * 4);
    int*   s_src  = (int*)carve((size_t)E * 4);
    float* s_ae1  = (float*)carve((size_t)E * 4);
    float* s_ae2  = (float*)carve((size_t)E * 4);
    float* bufA   = (float*)carve((size_t)n * 64 * 4);  // h1, then h2
    float* bufB   = (float*)carve((size_t)n * 64 * 4);  // relu(gat1 out)
    float* a_src1 = (float*)carve((size_t)n * 4);
    float* a_dst1 = (float*)carve((size_t)n * 4);
    float* a_src2 = (float*)carve((size_t)n * 4);
    float* a_dst2 = (float*)carve((size_t)n * 4);

    hipMemsetAsync(cnt, 0, (size_t)n * 4, stream);

    we_kernel<<<1, 64, 0, stream>>>(We1, att_edge1, We2, att_edge2, we1, we2);

    int egrid = (E + 255) / 256;
    edge_kernel<<<egrid, 256, 0, stream>>>((const float4*)eattr, eidx, we1, we2,
                                           ae1, ae2, cnt, E);

    scan_kernel<<<1, 1024, 0, stream>>>(cnt, row_ptr, cursor, n);

    scatter_kernel<<<egrid, 256, 0, stream>>>(eidx, ae1, ae2, cursor,
                                              s_src, s_ae1, s_ae2, E);

    int ngrid = (n + 3) / 4;
    // layer 1
    gemm_kernel<128><<<ngrid, 256, 0, stream>>>(x, W1, att_src1, att_dst1,
                                                bufA, a_src1, a_dst1, n);
    agg_kernel<true><<<ngrid, 256, 0, stream>>>(row_ptr, s_src, s_ae1, a_src1,
                                                a_dst1, bufA, b1, bufB, n);
    // layer 2
    gemm_kernel<64><<<ngrid, 256, 0, stream>>>(bufB, W2, att_src2, att_dst2,
                                               bufA, a_src2, a_dst2, n);
    agg_kernel<false><<<ngrid, 256, 0, stream>>>(row_ptr, s_src, s_ae2, a_src2,
                                                 a_dst2, bufA, b2, out, n);
}

// Round 2
// 454.025 us; speedup vs baseline: 1.4678x; 1.4678x over previous
//
#include <hip/hip_runtime.h>
#include <hip/hip_bf16.h>

// ---------------------------------------------------------------------------
// we[k] = sum_c We[k][c] * att_edge[c]  (per layer, 32 values each)
// ---------------------------------------------------------------------------
__global__ void we_kernel(const float* __restrict__ We1, const float* __restrict__ ae1v,
                          const float* __restrict__ We2, const float* __restrict__ ae2v,
                          float* __restrict__ we1, float* __restrict__ we2) {
    int t = threadIdx.x;            // 64 threads
    const float* W = (t < 32) ? We1 : We2;
    const float* a = (t < 32) ? ae1v : ae2v;
    float* o       = (t < 32) ? we1 : we2;
    int k = t & 31;
    float s = 0.f;
    for (int c = 0; c < 64; ++c) s += W[k * 64 + c] * a[c];
    o[k] = s;
}

// ---------------------------------------------------------------------------
// in-degree count
// ---------------------------------------------------------------------------
__global__ __launch_bounds__(256)
void count_kernel(const int* __restrict__ eidx, int* __restrict__ cnt, int E) {
    int e = blockIdx.x * 256 + threadIdx.x;
    if (e < E) atomicAdd(&cnt[eidx[E + e]], 1);
}

// ---------------------------------------------------------------------------
// scan stage A: per-256-chunk sums
// ---------------------------------------------------------------------------
__global__ __launch_bounds__(256)
void scanA_kernel(const int* __restrict__ cnt, int* __restrict__ bsum, int n) {
    int idx = blockIdx.x * 256 + threadIdx.x;
    int v = (idx < n) ? cnt[idx] : 0;
#pragma unroll
    for (int off = 32; off >= 1; off >>= 1) v += __shfl_xor(v, off, 64);
    __shared__ int ws[4];
    int lane = threadIdx.x & 63, wid = threadIdx.x >> 6;
    if (lane == 0) ws[wid] = v;
    __syncthreads();
    if (threadIdx.x == 0) bsum[blockIdx.x] = ws[0] + ws[1] + ws[2] + ws[3];
}

// ---------------------------------------------------------------------------
// scan stage B: exclusive scan of chunk sums (single wave)
// ---------------------------------------------------------------------------
__global__ void scanB_kernel(const int* __restrict__ bsum, int* __restrict__ boff, int nb) {
    int lane = threadIdx.x;   // 64
    int carry = 0;
    for (int base = 0; base < nb; base += 64) {
        int idx = base + lane;
        int v = (idx < nb) ? bsum[idx] : 0;
        int s = v;
#pragma unroll
        for (int off = 1; off < 64; off <<= 1) {
            int t = __shfl_up(s, off, 64);
            if (lane >= off) s += t;
        }
        if (idx < nb) boff[idx] = carry + s - v;
        carry += __shfl(s, 63, 64);
    }
}

// ---------------------------------------------------------------------------
// scan stage C: in-chunk scan + chunk offset -> row_ptr, cursor
// ---------------------------------------------------------------------------
__global__ __launch_bounds__(256)
void scanC_kernel(const int* __restrict__ cnt, const int* __restrict__ boff,
                  int* __restrict__ row_ptr, int* __restrict__ cursor, int n, int E) {
    __shared__ int ws[4];
    __shared__ int woff[4];
    int idx = blockIdx.x * 256 + threadIdx.x;
    int lane = threadIdx.x & 63, wid = threadIdx.x >> 6;
    int v = (idx < n) ? cnt[idx] : 0;
    int s = v;
#pragma unroll
    for (int off = 1; off < 64; off <<= 1) {
        int t = __shfl_up(s, off, 64);
        if (lane >= off) s += t;
    }
    if (lane == 63) ws[wid] = s;
    __syncthreads();
    if (threadIdx.x == 0) {
        int run = 0;
        for (int w = 0; w < 4; ++w) { int t = ws[w]; woff[w] = run; run += t; }
    }
    __syncthreads();
    if (idx < n) {
        int ex = boff[blockIdx.x] + woff[wid] + s - v;
        row_ptr[idx] = ex;
        cursor[idx] = ex;
    }
    if (idx == 0) row_ptr[n] = E;
}

// ---------------------------------------------------------------------------
// fused: per-edge a_edge for both layers + scatter into dst-sorted CSR
// record = {ae1, ae2, src_bits, 0}
// ---------------------------------------------------------------------------
__global__ __launch_bounds__(256)
void edge_scatter_kernel(const float4* __restrict__ ea, const int* __restrict__ eidx,
                         const float* __restrict__ we1g, const float* __restrict__ we2g,
                         int* __restrict__ cursor, float4* __restrict__ s_rec, int E) {
    __shared__ float w1s[32], w2s[32];
    if (threadIdx.x < 32) w1s[threadIdx.x] = we1g[threadIdx.x];
    else if (threadIdx.x < 64) w2s[threadIdx.x - 32] = we2g[threadIdx.x - 32];
    __syncthreads();
    int e = blockIdx.x * 256 + threadIdx.x;
    if (e >= E) return;
    float acc1 = 0.f, acc2 = 0.f;
#pragma unroll
    for (int q = 0; q < 8; ++q) {
        float4 v = ea[(size_t)e * 8 + q];
        acc1 += v.x * w1s[q * 4 + 0] + v.y * w1s[q * 4 + 1] +
                v.z * w1s[q * 4 + 2] + v.w * w1s[q * 4 + 3];
        acc2 += v.x * w2s[q * 4 + 0] + v.y * w2s[q * 4 + 1] +
                v.z * w2s[q * 4 + 2] + v.w * w2s[q * 4 + 3];
    }
    int src = eidx[e];
    int dst = eidx[E + e];
    int pos = atomicAdd(&cursor[dst], 1);
    s_rec[pos] = make_float4(acc1, acc2, __int_as_float(src), 0.f);
}

// ---------------------------------------------------------------------------
// H = X @ W (one wave per node, lane = out channel) + attn logit dots
// ---------------------------------------------------------------------------
template <int INC>
__global__ __launch_bounds__(256)
void gemm_kernel(const float* __restrict__ X, const float* __restrict__ W,
                 const float* __restrict__ asv, const float* __restrict__ adv,
                 float* __restrict__ H, float* __restrict__ a_src,
                 float* __restrict__ a_dst, int n) {
    __shared__ float Wl[INC * 64];
    for (int t = threadIdx.x; t < INC * 64; t += 256) Wl[t] = W[t];
    __syncthreads();
    int wid = threadIdx.x >> 6, lane = threadIdx.x & 63;
    int i = blockIdx.x * 4 + wid;
    if (i >= n) return;
    const float4* xr = (const float4*)(X + (size_t)i * INC);
    float acc = 0.f;
#pragma unroll
    for (int k4 = 0; k4 < INC / 4; ++k4) {
        float4 xv = xr[k4];
        acc += xv.x * Wl[(k4 * 4 + 0) * 64 + lane];
        acc += xv.y * Wl[(k4 * 4 + 1) * 64 + lane];
        acc += xv.z * Wl[(k4 * 4 + 2) * 64 + lane];
        acc += xv.w * Wl[(k4 * 4 + 3) * 64 + lane];
    }
    H[(size_t)i * 64 + lane] = acc;
    float s = acc * asv[lane];
    float d = acc * adv[lane];
#pragma unroll
    for (int off = 32; off >= 1; off >>= 1) {
        s += __shfl_xor(s, off, 64);
        d += __shfl_xor(d, off, 64);
    }
    if (lane == 0) { a_src[i] = s; a_dst[i] = d; }
}

// ---------------------------------------------------------------------------
// pass A: per-node softmax weights, lanes parallel over edges
// writes s_sw[j] = {src_bits, w=exp(al-m)}, wsd[i] = {wself, 1/(den+eps)}
// ---------------------------------------------------------------------------
template <int AEIDX>
__global__ __launch_bounds__(256)
void passA_kernel(const int* __restrict__ row_ptr, const float4* __restrict__ s_rec,
                  const float* __restrict__ a_srcv, const float* __restrict__ a_dstv,
                  float2* __restrict__ s_sw, float2* __restrict__ wsd, int n) {
    int wid = threadIdx.x >> 6, lane = threadIdx.x & 63;
    int i = blockIdx.x * 4 + wid;
    if (i >= n) return;
    int start = row_ptr[i], end = row_ptr[i + 1];
    int deg = end - start;
    float adst = a_dstv[i];
    float mloc = -INFINITY, aeloc = 0.f;
    float al0 = -INFINITY, al1 = -INFINITY;
    int src0 = 0, src1 = 0;
    { // chunk 0
        int j = start + lane;
        if (j < end) {
            float4 r = s_rec[j];
            float ae = (AEIDX == 0) ? r.x : r.y;
            src0 = __float_as_int(r.z);
            float a = a_srcv[src0] + adst + ae;
            al0 = a > 0.f ? a : 0.2f * a;
            aeloc += ae;
        }
        mloc = fmaxf(mloc, al0);
    }
    if (deg > 64) { // chunk 1
        int j = start + 64 + lane;
        if (j < end) {
            float4 r = s_rec[j];
            float ae = (AEIDX == 0) ? r.x : r.y;
            src1 = __float_as_int(r.z);
            float a = a_srcv[src1] + adst + ae;
            al1 = a > 0.f ? a : 0.2f * a;
            aeloc += ae;
        }
        mloc = fmaxf(mloc, al1);
    }
    for (int base = start + 128; base < end; base += 64) { // rare spill
        int j = base + lane;
        if (j < end) {
            float4 r = s_rec[j];
            float ae = (AEIDX == 0) ? r.x : r.y;
            int s = __float_as_int(r.z);
            float a = a_srcv[s] + adst + ae;
            a = a > 0.f ? a : 0.2f * a;
            mloc = fmaxf(mloc, a);
            aeloc += ae;
        }
    }
#pragma unroll
    for (int off = 32; off >= 1; off >>= 1) {
        mloc = fmaxf(mloc, __shfl_xor(mloc, off, 64));
        aeloc += __shfl_xor(aeloc, off, 64);
    }
    float ael = aeloc / (float)(deg > 0 ? deg : 1);
    float als = a_srcv[i] + adst + ael;
    als = als > 0.f ? als : 0.2f * als;
    float m = fmaxf(mloc, als);
    // phase 2: weights
    float dloc = 0.f;
    {
        int j = start + lane;
        if (j < end) {
            float w = __expf(al0 - m);
            s_sw[j] = make_float2(__int_as_float(src0), w);
            dloc += w;
        }
    }
    if (deg > 64) {
        int j = start + 64 + lane;
        if (j < end) {
            float w = __expf(al1 - m);
            s_sw[j] = make_float2(__int_as_float(src1), w);
            dloc += w;
        }
    }
    for (int base = start + 128; base < end; base += 64) {
        int j = base + lane;
        if (j < end) {
            float4 r = s_rec[j];
            float ae = (AEIDX == 0) ? r.x : r.y;
            int s = __float_as_int(r.z);
            float a = a_srcv[s] + adst + ae;
            a = a > 0.f ? a : 0.2f * a;
            float w = __expf(a - m);
            s_sw[j] = make_float2(r.z, w);
            dloc += w;
        }
    }
#pragma unroll
    for (int off = 32; off >= 1; off >>= 1) dloc += __shfl_xor(dloc, off, 64);
    if (lane == 0) {
        float wself = __expf(als - m);
        wsd[i] = make_float2(wself, 1.f / (dloc + wself + 1e-16f));
    }
}

// ---------------------------------------------------------------------------
// pass B: weighted gather-aggregate (one wave per node, lane = channel)
// ---------------------------------------------------------------------------
template <bool RELU>
__global__ __launch_bounds__(256)
void passB_kernel(const int* __restrict__ row_ptr, const float2* __restrict__ s_sw,
                  const float2* __restrict__ wsd, const float* __restrict__ H,
                  const float* __restrict__ bias, float* __restrict__ out, int n) {
    int wid = threadIdx.x >> 6, lane = threadIdx.x & 63;
    int i = blockIdx.x * 4 + wid;
    if (i >= n) return;
    int start = row_ptr[i], end = row_ptr[i + 1];
    float acc = 0.f;
#pragma unroll 4
    for (int j = start; j < end; ++j) {
        float2 sw = s_sw[j];                       // wave-uniform address -> broadcast
        int s = __float_as_int(sw.x);
        acc += sw.y * H[(size_t)s * 64 + lane];    // coalesced 256B row gather
    }
    float2 wd = wsd[i];
    acc += wd.x * H[(size_t)i * 64 + lane];
    float o = acc * wd.y + bias[lane];
    if (RELU) o = fmaxf(o, 0.f);
    out[(size_t)i * 64 + lane] = o;
}

// ---------------------------------------------------------------------------
extern "C" void kernel_launch(void* const* d_in, const int* in_sizes, int n_in,
                              void* d_out, int out_size, void* d_ws, size_t ws_size,
                              hipStream_t stream) {
    const float* x        = (const float*)d_in[0];
    const int*   eidx     = (const int*)d_in[1];
    const float* eattr    = (const float*)d_in[2];
    const float* W1       = (const float*)d_in[3];
    const float* We1      = (const float*)d_in[4];
    const float* att_src1 = (const float*)d_in[5];
    const float* att_dst1 = (const float*)d_in[6];
    const float* att_edge1= (const float*)d_in[7];
    const float* b1       = (const float*)d_in[8];
    const float* W2       = (const float*)d_in[9];
    const float* We2      = (const float*)d_in[10];
    const float* att_src2 = (const float*)d_in[11];
    const float* att_dst2 = (const float*)d_in[12];
    const float* att_edge2= (const float*)d_in[13];
    const float* b2       = (const float*)d_in[14];
    float* out = (float*)d_out;

    const int n = in_sizes[0] / 128;    // 50000
    const int E = in_sizes[1] / 2;      // 1600000

    char* ws = (char*)d_ws;
    size_t off = 0;
    auto carve = [&](size_t bytes) {
        char* p = ws + off;
        off = (off + bytes + 255) & ~(size_t)255;
        return p;
    };
    const int nblkScan = (n + 255) / 256;
    float*  we1    = (float*)carve(32 * 4);
    float*  we2    = (float*)carve(32 * 4);
    int*    cnt    = (int*)carve((size_t)n * 4);
    int*    bsum   = (int*)carve((size_t)nblkScan * 4);
    int*    boff   = (int*)carve((size_t)nblkScan * 4);
    int*    row_ptr= (int*)carve((size_t)(n + 1) * 4);
    int*    cursor = (int*)carve((size_t)n * 4);
    float4* s_rec  = (float4*)carve((size_t)E * 16);
    float2* s_sw   = (float2*)carve((size_t)E * 8);
    float2* wsd    = (float2*)carve((size_t)n * 8);
    float*  bufA   = (float*)carve((size_t)n * 64 * 4);  // H (both layers)
    float*  bufB   = (float*)carve((size_t)n * 64 * 4);  // relu(gat1 out)
    float*  a_src  = (float*)carve((size_t)n * 4);
    float*  a_dst  = (float*)carve((size_t)n * 4);

    hipMemsetAsync(cnt, 0, (size_t)n * 4, stream);

    we_kernel<<<1, 64, 0, stream>>>(We1, att_edge1, We2, att_edge2, we1, we2);

    int egrid = (E + 255) / 256;
    count_kernel<<<egrid, 256, 0, stream>>>(eidx, cnt, E);
    scanA_kernel<<<nblkScan, 256, 0, stream>>>(cnt, bsum, n);
    scanB_kernel<<<1, 64, 0, stream>>>(bsum, boff, nblkScan);
    scanC_kernel<<<nblkScan, 256, 0, stream>>>(cnt, boff, row_ptr, cursor, n, E);

    edge_scatter_kernel<<<egrid, 256, 0, stream>>>((const float4*)eattr, eidx,
                                                   we1, we2, cursor, s_rec, E);

    int ngrid = (n + 3) / 4;
    // layer 1
    gemm_kernel<128><<<ngrid, 256, 0, stream>>>(x, W1, att_src1, att_dst1,
                                                bufA, a_src, a_dst, n);
    passA_kernel<0><<<ngrid, 256, 0, stream>>>(row_ptr, s_rec, a_src, a_dst,
                                               s_sw, wsd, n);
    passB_kernel<true><<<ngrid, 256, 0, stream>>>(row_ptr, s_sw, wsd, bufA,
                                                  b1, bufB, n);
    // layer 2
    gemm_kernel<64><<<ngrid, 256, 0, stream>>>(bufB, W2, att_src2, att_dst2,
                                               bufA, a_src, a_dst, n);
    passA_kernel<1><<<ngrid, 256, 0, stream>>>(row_ptr, s_rec, a_src, a_dst,
                                               s_sw, wsd, n);
    passB_kernel<false><<<ngrid, 256, 0, stream>>>(row_ptr, s_sw, wsd, bufA,
                                                   b2, out, n);
}

// Round 4
// 412.963 us; speedup vs baseline: 1.6137x; 1.0994x over previous
//
#include <hip/hip_runtime.h>
#include <hip/hip_bf16.h>

// ---------------------------------------------------------------------------
// we[k] = sum_c We[k][c] * att_edge[c]  (per layer, 32 values each)
// ---------------------------------------------------------------------------
__global__ void we_kernel(const float* __restrict__ We1, const float* __restrict__ ae1v,
                          const float* __restrict__ We2, const float* __restrict__ ae2v,
                          float* __restrict__ we1, float* __restrict__ we2) {
    int t = threadIdx.x;            // 64 threads
    const float* W = (t < 32) ? We1 : We2;
    const float* a = (t < 32) ? ae1v : ae2v;
    float* o       = (t < 32) ? we1 : we2;
    int k = t & 31;
    float s = 0.f;
    for (int c = 0; c < 64; ++c) s += W[k * 64 + c] * a[c];
    o[k] = s;
}

// ---------------------------------------------------------------------------
// in-degree count
// ---------------------------------------------------------------------------
__global__ __launch_bounds__(256)
void count_kernel(const int* __restrict__ eidx, int* __restrict__ cnt, int E) {
    int e = blockIdx.x * 256 + threadIdx.x;
    if (e < E) atomicAdd(&cnt[eidx[E + e]], 1);
}

// ---------------------------------------------------------------------------
// scan stage A: per-256-chunk sums
// ---------------------------------------------------------------------------
__global__ __launch_bounds__(256)
void scanA_kernel(const int* __restrict__ cnt, int* __restrict__ bsum, int n) {
    int idx = blockIdx.x * 256 + threadIdx.x;
    int v = (idx < n) ? cnt[idx] : 0;
#pragma unroll
    for (int off = 32; off >= 1; off >>= 1) v += __shfl_xor(v, off, 64);
    __shared__ int ws[4];
    int lane = threadIdx.x & 63, wid = threadIdx.x >> 6;
    if (lane == 0) ws[wid] = v;
    __syncthreads();
    if (threadIdx.x == 0) bsum[blockIdx.x] = ws[0] + ws[1] + ws[2] + ws[3];
}

// ---------------------------------------------------------------------------
// scan stage B: exclusive scan of chunk sums (single wave)
// ---------------------------------------------------------------------------
__global__ void scanB_kernel(const int* __restrict__ bsum, int* __restrict__ boff, int nb) {
    int lane = threadIdx.x;   // 64
    int carry = 0;
    for (int base = 0; base < nb; base += 64) {
        int idx = base + lane;
        int v = (idx < nb) ? bsum[idx] : 0;
        int s = v;
#pragma unroll
        for (int off = 1; off < 64; off <<= 1) {
            int t = __shfl_up(s, off, 64);
            if (lane >= off) s += t;
        }
        if (idx < nb) boff[idx] = carry + s - v;
        carry += __shfl(s, 63, 64);
    }
}

// ---------------------------------------------------------------------------
// scan stage C: in-chunk scan + chunk offset -> row_ptr, cursor
// ---------------------------------------------------------------------------
__global__ __launch_bounds__(256)
void scanC_kernel(const int* __restrict__ cnt, const int* __restrict__ boff,
                  int* __restrict__ row_ptr, int* __restrict__ cursor, int n, int E) {
    __shared__ int ws[4];
    __shared__ int woff[4];
    int idx = blockIdx.x * 256 + threadIdx.x;
    int lane = threadIdx.x & 63, wid = threadIdx.x >> 6;
    int v = (idx < n) ? cnt[idx] : 0;
    int s = v;
#pragma unroll
    for (int off = 1; off < 64; off <<= 1) {
        int t = __shfl_up(s, off, 64);
        if (lane >= off) s += t;
    }
    if (lane == 63) ws[wid] = s;
    __syncthreads();
    if (threadIdx.x == 0) {
        int run = 0;
        for (int w = 0; w < 4; ++w) { int t = ws[w]; woff[w] = run; run += t; }
    }
    __syncthreads();
    if (idx < n) {
        int ex = boff[blockIdx.x] + woff[wid] + s - v;
        row_ptr[idx] = ex;
        cursor[idx] = ex;
    }
    if (idx == 0) row_ptr[n] = E;
}

// ---------------------------------------------------------------------------
// fused: per-edge a_edge for both layers + scatter into dst-sorted CSR
// record = {ae1, ae2, src_bits, 0}
// ---------------------------------------------------------------------------
__global__ __launch_bounds__(256)
void edge_scatter_kernel(const float4* __restrict__ ea, const int* __restrict__ eidx,
                         const float* __restrict__ we1g, const float* __restrict__ we2g,
                         int* __restrict__ cursor, float4* __restrict__ s_rec, int E) {
    __shared__ float w1s[32], w2s[32];
    if (threadIdx.x < 32) w1s[threadIdx.x] = we1g[threadIdx.x];
    else if (threadIdx.x < 64) w2s[threadIdx.x - 32] = we2g[threadIdx.x - 32];
    __syncthreads();
    int e = blockIdx.x * 256 + threadIdx.x;
    if (e >= E) return;
    float acc1 = 0.f, acc2 = 0.f;
#pragma unroll
    for (int q = 0; q < 8; ++q) {
        float4 v = ea[(size_t)e * 8 + q];
        acc1 += v.x * w1s[q * 4 + 0] + v.y * w1s[q * 4 + 1] +
                v.z * w1s[q * 4 + 2] + v.w * w1s[q * 4 + 3];
        acc2 += v.x * w2s[q * 4 + 0] + v.y * w2s[q * 4 + 1] +
                v.z * w2s[q * 4 + 2] + v.w * w2s[q * 4 + 3];
    }
    int src = eidx[e];
    int dst = eidx[E + e];
    int pos = atomicAdd(&cursor[dst], 1);
    s_rec[pos] = make_float4(acc1, acc2, __int_as_float(src), 0.f);
}

// ---------------------------------------------------------------------------
// H = X @ W (one wave per node, lane = out channel) + attn logit dots
// ---------------------------------------------------------------------------
template <int INC>
__global__ __launch_bounds__(256)
void gemm_kernel(const float* __restrict__ X, const float* __restrict__ W,
                 const float* __restrict__ asv, const float* __restrict__ adv,
                 float* __restrict__ H, float* __restrict__ a_src,
                 float* __restrict__ a_dst, int n) {
    __shared__ float Wl[INC * 64];
    for (int t = threadIdx.x; t < INC * 64; t += 256) Wl[t] = W[t];
    __syncthreads();
    int wid = threadIdx.x >> 6, lane = threadIdx.x & 63;
    int i = blockIdx.x * 4 + wid;
    if (i >= n) return;
    const float4* xr = (const float4*)(X + (size_t)i * INC);
    float acc = 0.f;
#pragma unroll
    for (int k4 = 0; k4 < INC / 4; ++k4) {
        float4 xv = xr[k4];
        acc += xv.x * Wl[(k4 * 4 + 0) * 64 + lane];
        acc += xv.y * Wl[(k4 * 4 + 1) * 64 + lane];
        acc += xv.z * Wl[(k4 * 4 + 2) * 64 + lane];
        acc += xv.w * Wl[(k4 * 4 + 3) * 64 + lane];
    }
    H[(size_t)i * 64 + lane] = acc;
    float s = acc * asv[lane];
    float d = acc * adv[lane];
#pragma unroll
    for (int off = 32; off >= 1; off >>= 1) {
        s += __shfl_xor(s, off, 64);
        d += __shfl_xor(d, off, 64);
    }
    if (lane == 0) { a_src[i] = s; a_dst[i] = d; }
}

// ---------------------------------------------------------------------------
// fused aggregation: softmax weights in registers (lane = edge), then
// gather phase as wave = 4 edge-slots x 16 channel-quads (float4 loads)
// ---------------------------------------------------------------------------
template <int AEIDX, bool RELU>
__global__ __launch_bounds__(256)
void agg_fused_kernel(const int* __restrict__ row_ptr, const float4* __restrict__ s_rec,
                      const float* __restrict__ a_srcv, const float* __restrict__ a_dstv,
                      const float4* __restrict__ H4, const float* __restrict__ bias,
                      float* __restrict__ out, int n) {
    int wid = threadIdx.x >> 6, lane = threadIdx.x & 63;
    int i = blockIdx.x * 4 + wid;
    if (i >= n) return;
    int start = row_ptr[i], end = row_ptr[i + 1];
    int deg = end - start;
    float adst = a_dstv[i];

    // ---- phase 1: logits (lane = edge), deg<=128 fast path in regs ----
    float al0 = -INFINITY, al1 = -INFINITY;
    int src0 = 0, src1 = 0;
    float aeloc = 0.f;
    {
        int j = start + lane;
        if (j < end) {
            float4 r = s_rec[j];
            float ae = (AEIDX == 0) ? r.x : r.y;
            src0 = __float_as_int(r.z);
            float a = a_srcv[src0] + adst + ae;
            al0 = a > 0.f ? a : 0.2f * a;
            aeloc += ae;
        }
    }
    if (deg > 64) {
        int j = start + 64 + lane;
        if (j < end) {
            float4 r = s_rec[j];
            float ae = (AEIDX == 0) ? r.x : r.y;
            src1 = __float_as_int(r.z);
            float a = a_srcv[src1] + adst + ae;
            al1 = a > 0.f ? a : 0.2f * a;
            aeloc += ae;
        }
    }
    float mloc = fmaxf(al0, al1);
    for (int base = start + 128; base < end; base += 64) {   // rare spill
        int j = base + lane;
        if (j < end) {
            float4 r = s_rec[j];
            float ae = (AEIDX == 0) ? r.x : r.y;
            int s = __float_as_int(r.z);
            float a = a_srcv[s] + adst + ae;
            a = a > 0.f ? a : 0.2f * a;
            mloc = fmaxf(mloc, a);
            aeloc += ae;
        }
    }
#pragma unroll
    for (int off = 32; off >= 1; off >>= 1) {
        mloc = fmaxf(mloc, __shfl_xor(mloc, off, 64));
        aeloc += __shfl_xor(aeloc, off, 64);
    }
    float ael = aeloc / (float)(deg > 0 ? deg : 1);
    float als = a_srcv[i] + adst + ael;
    als = als > 0.f ? als : 0.2f * als;
    float m = fmaxf(mloc, als);

    float w0 = (start + lane < end)      ? __expf(al0 - m) : 0.f;
    float w1 = (start + 64 + lane < end) ? __expf(al1 - m) : 0.f;
    float dloc = w0 + w1;
    for (int base = start + 128; base < end; base += 64) {   // rare spill
        int j = base + lane;
        if (j < end) {
            float4 r = s_rec[j];
            float ae = (AEIDX == 0) ? r.x : r.y;
            int s = __float_as_int(r.z);
            float a = a_srcv[s] + adst + ae;
            a = a > 0.f ? a : 0.2f * a;
            dloc += __expf(a - m);
        }
    }
#pragma unroll
    for (int off = 32; off >= 1; off >>= 1) dloc += __shfl_xor(dloc, off, 64);
    float wself = __expf(als - m);
    float inv = 1.f / (dloc + wself + 1e-16f);

    // ---- phase 2: gather. wave = 4 edge-slots x 16 channel-quads ----
    int sub = lane >> 4;          // edge slot 0..3
    int c4  = lane & 15;          // channel quad
    float4 acc = make_float4(0.f, 0.f, 0.f, 0.f);
    int mainCnt = deg < 128 ? deg : 128;
    for (int r = 0; r < mainCnt; r += 4) {
        int rel = r + sub;                 // 0..127 (may overrun tail: w==0 there)
        float wa = __shfl(w0, rel & 63, 64);
        float wb = __shfl(w1, rel & 63, 64);
        int   sa = __shfl(src0, rel & 63, 64);
        int   sb = __shfl(src1, rel & 63, 64);
        float w = (rel < 64) ? wa : wb;
        int   s = (rel < 64) ? sa : sb;
        float4 hv = H4[(size_t)s * 16 + c4];
        acc.x += w * hv.x; acc.y += w * hv.y;
        acc.z += w * hv.z; acc.w += w * hv.w;
    }
    for (int j = start + 128; j < end; j += 4) {   // rare spill: recompute w
        int jj = j + sub;
        if (jj < end) {
            float4 r = s_rec[jj];
            float ae = (AEIDX == 0) ? r.x : r.y;
            int s = __float_as_int(r.z);
            float a = a_srcv[s] + adst + ae;
            a = a > 0.f ? a : 0.2f * a;
            float w = __expf(a - m);
            float4 hv = H4[(size_t)s * 16 + c4];
            acc.x += w * hv.x; acc.y += w * hv.y;
            acc.z += w * hv.z; acc.w += w * hv.w;
        }
    }
    // reduce across the 4 edge-slots (lanes differing in bits 4,5)
#pragma unroll
    for (int off = 16; off <= 32; off <<= 1) {
        acc.x += __shfl_xor(acc.x, off, 64);
        acc.y += __shfl_xor(acc.y, off, 64);
        acc.z += __shfl_xor(acc.z, off, 64);
        acc.w += __shfl_xor(acc.w, off, 64);
    }
    // self-loop + epilogue (all lanes consistent)
    float4 hv = H4[(size_t)i * 16 + c4];
    float4 bv = ((const float4*)bias)[c4];
    float4 o;
    o.x = (acc.x + wself * hv.x) * inv + bv.x;
    o.y = (acc.y + wself * hv.y) * inv + bv.y;
    o.z = (acc.z + wself * hv.z) * inv + bv.z;
    o.w = (acc.w + wself * hv.w) * inv + bv.w;
    if (RELU) {
        o.x = fmaxf(o.x, 0.f); o.y = fmaxf(o.y, 0.f);
        o.z = fmaxf(o.z, 0.f); o.w = fmaxf(o.w, 0.f);
    }
    if (sub == 0) ((float4*)out)[(size_t)i * 16 + c4] = o;
}

// ---------------------------------------------------------------------------
extern "C" void kernel_launch(void* const* d_in, const int* in_sizes, int n_in,
                              void* d_out, int out_size, void* d_ws, size_t ws_size,
                              hipStream_t stream) {
    const float* x        = (const float*)d_in[0];
    const int*   eidx     = (const int*)d_in[1];
    const float* eattr    = (const float*)d_in[2];
    const float* W1       = (const float*)d_in[3];
    const float* We1      = (const float*)d_in[4];
    const float* att_src1 = (const float*)d_in[5];
    const float* att_dst1 = (const float*)d_in[6];
    const float* att_edge1= (const float*)d_in[7];
    const float* b1       = (const float*)d_in[8];
    const float* W2       = (const float*)d_in[9];
    const float* We2      = (const float*)d_in[10];
    const float* att_src2 = (const float*)d_in[11];
    const float* att_dst2 = (const float*)d_in[12];
    const float* att_edge2= (const float*)d_in[13];
    const float* b2       = (const float*)d_in[14];
    float* out = (float*)d_out;

    const int n = in_sizes[0] / 128;    // 50000
    const int E = in_sizes[1] / 2;      // 1600000

    char* ws = (char*)d_ws;
    size_t off = 0;
    auto carve = [&](size_t bytes) {
        char* p = ws + off;
        off = (off + bytes + 255) & ~(size_t)255;
        return p;
    };
    const int nblkScan = (n + 255) / 256;
    float*  we1    = (float*)carve(32 * 4);
    float*  we2    = (float*)carve(32 * 4);
    int*    cnt    = (int*)carve((size_t)n * 4);
    int*    bsum   = (int*)carve((size_t)nblkScan * 4);
    int*    boff   = (int*)carve((size_t)nblkScan * 4);
    int*    row_ptr= (int*)carve((size_t)(n + 1) * 4);
    int*    cursor = (int*)carve((size_t)n * 4);
    float4* s_rec  = (float4*)carve((size_t)E * 16);
    float*  bufA   = (float*)carve((size_t)n * 64 * 4);  // H (both layers)
    float*  bufB   = (float*)carve((size_t)n * 64 * 4);  // relu(gat1 out)
    float*  a_src  = (float*)carve((size_t)n * 4);
    float*  a_dst  = (float*)carve((size_t)n * 4);

    hipMemsetAsync(cnt, 0, (size_t)n * 4, stream);

    we_kernel<<<1, 64, 0, stream>>>(We1, att_edge1, We2, att_edge2, we1, we2);

    int egrid = (E + 255) / 256;
    count_kernel<<<egrid, 256, 0, stream>>>(eidx, cnt, E);
    scanA_kernel<<<nblkScan, 256, 0, stream>>>(cnt, bsum, n);
    scanB_kernel<<<1, 64, 0, stream>>>(bsum, boff, nblkScan);
    scanC_kernel<<<nblkScan, 256, 0, stream>>>(cnt, boff, row_ptr, cursor, n, E);

    edge_scatter_kernel<<<egrid, 256, 0, stream>>>((const float4*)eattr, eidx,
                                                   we1, we2, cursor, s_rec, E);

    int ngrid = (n + 3) / 4;
    // layer 1
    gemm_kernel<128><<<ngrid, 256, 0, stream>>>(x, W1, att_src1, att_dst1,
                                                bufA, a_src, a_dst, n);
    agg_fused_kernel<0, true><<<ngrid, 256, 0, stream>>>(row_ptr, s_rec, a_src,
                                                         a_dst, (const float4*)bufA,
                                                         b1, bufB, n);
    // layer 2
    gemm_kernel<64><<<ngrid, 256, 0, stream>>>(bufB, W2, att_src2, att_dst2,
                                               bufA, a_src, a_dst, n);
    agg_fused_kernel<1, false><<<ngrid, 256, 0, stream>>>(row_ptr, s_rec, a_src,
                                                          a_dst, (const float4*)bufA,
                                                          b2, out, n);
}